// Round 1
// baseline (953.446 us; speedup 1.0000x reference)
//
#include <hip/hip_runtime.h>
#include <hip/hip_bf16.h>
#include <math.h>

#define C_NUM 345
#define A_DIM 512
#define N_NUM 128
#define MT 64
#define NT 128
#define KT 32
#define CBLK 6  // ceil(345/64)

// Kernel A: q[n,c] = (w_c - w_l)^T Sigma_l (w_c - w_l), l = labels[n]
// Tiled as fused GEMM: t = V @ Sigma (M=64-tile, N=128-tile, K=32-tile),
// epilogue dots t-tile with V-tile into per-row partials.
__global__ __launch_bounds__(256) void qkern(
    const float* __restrict__ W,     // [C, A]
    const int*   __restrict__ labels,// [N]
    const float* __restrict__ cov,   // [C, A, A]
    float*       __restrict__ q)     // [N, C] workspace
{
    const int n  = blockIdx.y;
    const int c0 = blockIdx.x * MT;
    const int l  = labels[n];
    const float* Sg = cov + (size_t)l * A_DIM * A_DIM;
    const float* Wl = W + (size_t)l * A_DIM;

    // Vt padded to 36 floats/row: row stride 144 B (16B-aligned for float4
    // writes); GEMM reads Vt[ty*4+i][k] land 2-way max per bank (free).
    __shared__ float Vt[MT][KT + 4];
    __shared__ float S[KT][NT];

    const int tid = threadIdx.x;
    const int tx = tid & 15;   // 0..15 -> column groups (stride-16 cols)
    const int ty = tid >> 4;   // 0..15 -> row groups (4 rows each)

    float qpart[4] = {0.f, 0.f, 0.f, 0.f};

    for (int bt = 0; bt < A_DIM; bt += NT) {
        float acc[4][8];
#pragma unroll
        for (int i = 0; i < 4; i++)
#pragma unroll
            for (int j = 0; j < 8; j++) acc[i][j] = 0.f;

        for (int kt = 0; kt < A_DIM; kt += KT) {
            // Stage S[32][128]: 1024 float4, 4 per thread, coalesced rows.
            {
                const int c4 = tid & 31;   // float4 col 0..31
                const int r0 = tid >> 5;   // 0..7
#pragma unroll
                for (int it = 0; it < 4; it++) {
                    const int row = r0 + it * 8;  // 0..31
                    const float4 v = *(const float4*)(Sg + (size_t)(kt + row) * A_DIM + bt + c4 * 4);
                    *(float4*)(&S[row][c4 * 4]) = v;
                }
            }
            // Stage Vt[64][32] = W[c0+row][kt..] - Wl[kt..]: 512 float4, 2/thread.
            {
                const int c4 = tid & 7;   // float4 col 0..7
                const int r0 = tid >> 3;  // 0..31
#pragma unroll
                for (int it = 0; it < 2; it++) {
                    const int row = r0 + it * 32;  // 0..63
                    const int c = c0 + row;
                    const float4 wl4 = *(const float4*)(Wl + kt + c4 * 4);
                    float4 wv;
                    if (c < C_NUM) {
                        wv = *(const float4*)(W + (size_t)c * A_DIM + kt + c4 * 4);
                        wv.x -= wl4.x; wv.y -= wl4.y; wv.z -= wl4.z; wv.w -= wl4.w;
                    } else {
                        wv = make_float4(0.f, 0.f, 0.f, 0.f);
                    }
                    *(float4*)(&Vt[row][c4 * 4]) = wv;
                }
            }
            __syncthreads();
#pragma unroll
            for (int k = 0; k < KT; k++) {
                float a[4], b[8];
#pragma unroll
                for (int i = 0; i < 4; i++) a[i] = Vt[ty * 4 + i][k];
#pragma unroll
                for (int j = 0; j < 8; j++) b[j] = S[k][tx + 16 * j];
#pragma unroll
                for (int i = 0; i < 4; i++)
#pragma unroll
                    for (int j = 0; j < 8; j++)
                        acc[i][j] = fmaf(a[i], b[j], acc[i][j]);
            }
            __syncthreads();
        }
        // Epilogue for this b-tile: q[c] += sum_b t[c,b] * v[c,b].
        // v re-read from global (W is ~700KB, hot in L1/L2).
#pragma unroll
        for (int i = 0; i < 4; i++) {
            const int c = c0 + ty * 4 + i;
            if (c < C_NUM) {
                const float* wr = W + (size_t)c * A_DIM + bt;
#pragma unroll
                for (int j = 0; j < 8; j++) {
                    const int col = tx + 16 * j;
                    const float v = wr[col] - Wl[bt + col];
                    qpart[i] = fmaf(acc[i][j], v, qpart[i]);
                }
            }
        }
    }
    // Reduce qpart across the 16 tx lanes (xor masks stay within 16-groups).
#pragma unroll
    for (int i = 0; i < 4; i++) {
        float p = qpart[i];
        p += __shfl_xor(p, 1);
        p += __shfl_xor(p, 2);
        p += __shfl_xor(p, 4);
        p += __shfl_xor(p, 8);
        if (tx == 0) {
            const int c = c0 + ty * 4 + i;
            if (c < C_NUM) q[n * C_NUM + c] = p;
        }
    }
}

// Kernel B: aug = y_s + 0.5*Lambda*q + Lambda*(w_c . dm - w_l . dm);
// nll_n = logsumexp(aug) - aug[l]; out = mean(nll).
__global__ __launch_bounds__(256) void losskern(
    const float* __restrict__ W,
    const float* __restrict__ ys,
    const int*   __restrict__ labels,
    const float* __restrict__ lambda_p,
    const float* __restrict__ mean_s,
    const float* __restrict__ mean_t,
    const float* __restrict__ q,
    float*       __restrict__ out)
{
    const int n = blockIdx.x;
    const int tid = threadIdx.x;
    const int l = labels[n];
    const float Lam = *lambda_p;

    __shared__ float dm[A_DIM];
    __shared__ float red[256];
    __shared__ float aug[C_NUM];

    for (int a = tid; a < A_DIM; a += 256)
        dm[a] = mean_t[(size_t)l * A_DIM + a] - mean_s[(size_t)l * A_DIM + a];
    __syncthreads();

    // wl . dm
    float local = 0.f;
    for (int a = tid; a < A_DIM; a += 256)
        local = fmaf(W[(size_t)l * A_DIM + a], dm[a], local);
    red[tid] = local;
    __syncthreads();
    for (int s = 128; s > 0; s >>= 1) {
        if (tid < s) red[tid] += red[tid + s];
        __syncthreads();
    }
    const float wldm = red[0];
    __syncthreads();

    for (int c = tid; c < C_NUM; c += 256) {
        const float* wr = W + (size_t)c * A_DIM;
        float dp = 0.f;
        for (int a = 0; a < A_DIM; a++) dp = fmaf(wr[a], dm[a], dp);
        aug[c] = ys[n * C_NUM + c] + 0.5f * Lam * q[n * C_NUM + c] + Lam * (dp - wldm);
    }
    __syncthreads();

    float m = -INFINITY;
    for (int c = tid; c < C_NUM; c += 256) m = fmaxf(m, aug[c]);
    red[tid] = m;
    __syncthreads();
    for (int s = 128; s > 0; s >>= 1) {
        if (tid < s) red[tid] = fmaxf(red[tid], red[tid + s]);
        __syncthreads();
    }
    m = red[0];
    __syncthreads();

    float se = 0.f;
    for (int c = tid; c < C_NUM; c += 256) se += expf(aug[c] - m);
    red[tid] = se;
    __syncthreads();
    for (int s = 128; s > 0; s >>= 1) {
        if (tid < s) red[tid] += red[tid + s];
        __syncthreads();
    }
    if (tid == 0) {
        const float logZ = m + logf(red[0]);
        const float nll = logZ - aug[l];
        atomicAdd(out, nll * (1.f / N_NUM));
    }
}

extern "C" void kernel_launch(void* const* d_in, const int* in_sizes, int n_in,
                              void* d_out, int out_size, void* d_ws, size_t ws_size,
                              hipStream_t stream) {
    const float* W      = (const float*)d_in[0];
    // d_in[1] = features_source: unused by the reference.
    const float* ys     = (const float*)d_in[2];
    const int*   labels = (const int*)d_in[3];
    const float* lam    = (const float*)d_in[4];
    const float* means  = (const float*)d_in[5];
    const float* meant  = (const float*)d_in[6];
    const float* cov    = (const float*)d_in[7];
    float* out = (float*)d_out;
    float* q   = (float*)d_ws;  // N*C floats = 706,560 B

    // d_out is poisoned 0xAA before every timed launch; zero it ourselves.
    hipMemsetAsync(out, 0, sizeof(float), stream);

    dim3 gA(CBLK, N_NUM);
    qkern<<<gA, 256, 0, stream>>>(W, labels, cov, q);
    losskern<<<N_NUM, 256, 0, stream>>>(W, ys, labels, lam, means, meant, q, out);
}

// Round 2
// 555.211 us; speedup vs baseline: 1.7173x; 1.7173x over previous
//
#include <hip/hip_runtime.h>
#include <hip/hip_bf16.h>
#include <math.h>

#define C_NUM 345
#define A_DIM 512
#define N_NUM 128
#define KB    128   // b-range (GEMM K) per block
#define NBB   4     // blocks along b

typedef short bf16x8 __attribute__((ext_vector_type(8)));
typedef float f32x4  __attribute__((ext_vector_type(4)));

__device__ __forceinline__ short f2bf(float f) {
    unsigned u = __builtin_bit_cast(unsigned, f);
    u += 0x7fffu + ((u >> 16) & 1u);   // RNE
    return (short)(u >> 16);
}

// XOR-swizzled LDS index (in shorts): 128x128 bf16 tile, row stride 128.
// 16B chunks permuted by row -> frag reads/writes are <=2-way conflicts (free).
__device__ __forceinline__ int swz(int r, int k) {
    return r * 128 + ((((k >> 3) ^ (r & 15)) << 3) | (k & 7));
}

// q2[n,c] += sum_{a} sum_{b in block range} v[c,a] * Sigma_l[a,b] * v[c,b]
// via MFMA: u[a,c] = sum_b Sigma[a,b] * v[c,b]  (A = Sigma rows, B = V rows,
// both K(=b)-contiguous), epilogue dots u with v over a (4 consecutive a per
// acc reg quad -> float4 W reads).
__global__ __launch_bounds__(256, 2) void qkern(
    const float* __restrict__ W,      // [C, A]
    const int*   __restrict__ labels, // [N]
    const float* __restrict__ cov,    // [C, A, A]
    float*       __restrict__ q2)     // [N, C] accumulator (zeroed)
{
    const int bb = blockIdx.x;        // 0..3  (b-range)
    const int n  = blockIdx.y;        // 0..127
    const int b0 = bb * KB;
    const int l  = labels[n];
    const float* __restrict__ Sg = cov + (size_t)l * A_DIM * A_DIM;
    const float* __restrict__ Wl = W + (size_t)l * A_DIM;

    __shared__ short Sa[128 * 128];   // A: rows a (at-chunk), k = b
    __shared__ short Vb[128 * 128];   // B: rows c (ct-chunk), k = b

    const int tid  = threadIdx.x;
    const int lane = tid & 63;
    const int w    = tid >> 6;        // wave 0..3
    const int wa   = w & 1;           // a-half of 128-tile
    const int wc   = w >> 1;          // c-half of 128-tile
    const int l15  = lane & 15;
    const int g    = lane >> 4;       // 0..3

    // staging coords: 32 threads per row (float4 each), 8 rows per pass
    const int c4 = tid & 31;
    const int r0 = tid >> 5;

    // Wl over this block's b-range (reused in every Vb stage)
    const float4 wl4 = *(const float4*)(Wl + b0 + c4 * 4);

    float qp[3][4];
#pragma unroll
    for (int ct = 0; ct < 3; ct++)
#pragma unroll
        for (int j = 0; j < 4; j++) qp[ct][j] = 0.f;

    for (int at = 0; at < A_DIM; at += 128) {
        // epilogue Wl float4s for this at (reused across ct)
        float4 wle[4];
#pragma unroll
        for (int i = 0; i < 4; i++)
            wle[i] = *(const float4*)(Wl + at + wa * 64 + i * 16 + g * 4);

        for (int ct = 0; ct < 3; ct++) {
            __syncthreads();  // previous tile's readers done before overwrite
            if (ct == 0) {
                // stage Sa: Sigma[at..at+128) x [b0..b0+128)  (staged ONCE)
#pragma unroll
                for (int p = 0; p < 16; p++) {
                    const int r = r0 + p * 8;
                    const float4 s = *(const float4*)(Sg + (size_t)(at + r) * A_DIM + b0 + c4 * 4);
                    short4 h = make_short4(f2bf(s.x), f2bf(s.y), f2bf(s.z), f2bf(s.w));
                    *(short4*)(&Sa[swz(r, c4 * 4)]) = h;
                }
            }
            // stage Vb: v[c, b-range] for c-chunk ct (W is L2-hot, 706 KB)
#pragma unroll
            for (int p = 0; p < 16; p++) {
                const int r = r0 + p * 8;
                const int c = ct * 128 + r;
                short4 h;
                if (c < C_NUM) {
                    const float4 wv = *(const float4*)(W + (size_t)c * A_DIM + b0 + c4 * 4);
                    h = make_short4(f2bf(wv.x - wl4.x), f2bf(wv.y - wl4.y),
                                    f2bf(wv.z - wl4.z), f2bf(wv.w - wl4.w));
                } else {
                    h = make_short4(0, 0, 0, 0);
                }
                *(short4*)(&Vb[swz(r, c4 * 4)]) = h;
            }
            __syncthreads();

            f32x4 acc[4][4];
#pragma unroll
            for (int i = 0; i < 4; i++)
#pragma unroll
                for (int j = 0; j < 4; j++) {
                    f32x4 z = {0.f, 0.f, 0.f, 0.f};
                    acc[i][j] = z;
                }

#pragma unroll
            for (int kt = 0; kt < 4; kt++) {
                const int kbase = kt * 32 + g * 8;   // A/B frag: k = quad*8+j
                bf16x8 af[4], bfr[4];
#pragma unroll
                for (int i = 0; i < 4; i++)
                    af[i] = *(const bf16x8*)(&Sa[swz(wa * 64 + i * 16 + l15, kbase)]);
#pragma unroll
                for (int j = 0; j < 4; j++)
                    bfr[j] = *(const bf16x8*)(&Vb[swz(wc * 64 + j * 16 + l15, kbase)]);
#pragma unroll
                for (int i = 0; i < 4; i++)
#pragma unroll
                    for (int j = 0; j < 4; j++)
                        acc[i][j] = __builtin_amdgcn_mfma_f32_16x16x32_bf16(
                            af[i], bfr[j], acc[i][j], 0, 0, 0);
            }

            // epilogue: qp[c] += sum over this (at) of u[a,c]*v[c,a]
            // C/D layout: col(c) = lane&15, row(a) = g*4 + reg  -> float4 in a
#pragma unroll
            for (int i = 0; i < 4; i++) {
                const int a0 = at + wa * 64 + i * 16 + g * 4;
                const float4 wl_e = wle[i];
#pragma unroll
                for (int j = 0; j < 4; j++) {
                    const int c = ct * 128 + wc * 64 + j * 16 + l15;
                    if (c < C_NUM) {
                        const float4 wv = *(const float4*)(W + (size_t)c * A_DIM + a0);
                        const f32x4 u = acc[i][j];
                        qp[ct][j] += u[0] * (wv.x - wl_e.x) + u[1] * (wv.y - wl_e.y)
                                   + u[2] * (wv.z - wl_e.z) + u[3] * (wv.w - wl_e.w);
                    }
                }
            }
        }
    }

    // reduce over the 4 g-groups (same c, different a rows) and accumulate
#pragma unroll
    for (int ct = 0; ct < 3; ct++)
#pragma unroll
        for (int j = 0; j < 4; j++) {
            float v = qp[ct][j];
            v += __shfl_xor(v, 16);
            v += __shfl_xor(v, 32);
            if (g == 0) {
                const int c = ct * 128 + wc * 64 + j * 16 + l15;
                if (c < C_NUM) atomicAdd(&q2[(size_t)n * C_NUM + c], v);
            }
        }
}

// aug[c] = ys + 0.5*Lam*q2 + Lam*(w_c - w_l).dm ; nll = logsumexp - aug[l]
__global__ __launch_bounds__(256) void losskern(
    const float* __restrict__ W,
    const float* __restrict__ ys,
    const int*   __restrict__ labels,
    const float* __restrict__ lambda_p,
    const float* __restrict__ mean_s,
    const float* __restrict__ mean_t,
    const float* __restrict__ q2,
    float*       __restrict__ out)
{
    const int n = blockIdx.x;
    const int tid = threadIdx.x;
    const int lane = tid & 63;
    const int w = tid >> 6;
    const int l = labels[n];
    const float Lam = *lambda_p;

    __shared__ float aug[C_NUM];
    __shared__ float red[256];

    // per-lane 8-element slice of the A dimension
    const int a0 = lane * 8;
    const float* Wl = W + (size_t)l * A_DIM;
    const float4 wl0 = *(const float4*)(Wl + a0);
    const float4 wl1 = *(const float4*)(Wl + a0 + 4);
    const float4 mt0 = *(const float4*)(mean_t + (size_t)l * A_DIM + a0);
    const float4 mt1 = *(const float4*)(mean_t + (size_t)l * A_DIM + a0 + 4);
    const float4 ms0 = *(const float4*)(mean_s + (size_t)l * A_DIM + a0);
    const float4 ms1 = *(const float4*)(mean_s + (size_t)l * A_DIM + a0 + 4);
    const float dm0 = mt0.x - ms0.x, dm1 = mt0.y - ms0.y, dm2 = mt0.z - ms0.z, dm3 = mt0.w - ms0.w;
    const float dm4 = mt1.x - ms1.x, dm5 = mt1.y - ms1.y, dm6 = mt1.z - ms1.z, dm7 = mt1.w - ms1.w;
    const float wldm = wl0.x*dm0 + wl0.y*dm1 + wl0.z*dm2 + wl0.w*dm3
                     + wl1.x*dm4 + wl1.y*dm5 + wl1.z*dm6 + wl1.w*dm7;

    // wave-per-row dot products: wave w handles rows w, w+4, ...
    for (int c = w; c < C_NUM; c += 4) {
        const float* Wc = W + (size_t)c * A_DIM;
        const float4 w0 = *(const float4*)(Wc + a0);
        const float4 w1 = *(const float4*)(Wc + a0 + 4);
        float d = w0.x*dm0 + w0.y*dm1 + w0.z*dm2 + w0.w*dm3
                + w1.x*dm4 + w1.y*dm5 + w1.z*dm6 + w1.w*dm7 - wldm;
        d += __shfl_xor(d, 1);
        d += __shfl_xor(d, 2);
        d += __shfl_xor(d, 4);
        d += __shfl_xor(d, 8);
        d += __shfl_xor(d, 16);
        d += __shfl_xor(d, 32);
        if (lane == 0)
            aug[c] = ys[(size_t)n * C_NUM + c] + 0.5f * Lam * q2[(size_t)n * C_NUM + c] + Lam * d;
    }
    __syncthreads();

    float m = -INFINITY;
    for (int c = tid; c < C_NUM; c += 256) m = fmaxf(m, aug[c]);
    red[tid] = m;
    __syncthreads();
    for (int s = 128; s > 0; s >>= 1) {
        if (tid < s) red[tid] = fmaxf(red[tid], red[tid + s]);
        __syncthreads();
    }
    m = red[0];
    __syncthreads();

    float se = 0.f;
    for (int c = tid; c < C_NUM; c += 256) se += expf(aug[c] - m);
    red[tid] = se;
    __syncthreads();
    for (int s = 128; s > 0; s >>= 1) {
        if (tid < s) red[tid] += red[tid + s];
        __syncthreads();
    }
    if (tid == 0) {
        const float logZ = m + logf(red[0]);
        atomicAdd(out, (logZ - aug[l]) * (1.f / (float)N_NUM));
    }
}

extern "C" void kernel_launch(void* const* d_in, const int* in_sizes, int n_in,
                              void* d_out, int out_size, void* d_ws, size_t ws_size,
                              hipStream_t stream) {
    const float* W      = (const float*)d_in[0];
    // d_in[1] = features_source: unused by the reference.
    const float* ys     = (const float*)d_in[2];
    const int*   labels = (const int*)d_in[3];
    const float* lam    = (const float*)d_in[4];
    const float* means  = (const float*)d_in[5];
    const float* meant  = (const float*)d_in[6];
    const float* cov    = (const float*)d_in[7];
    float* out = (float*)d_out;
    float* q2  = (float*)d_ws;   // N*C floats = 706,560 B

    // ws and out are poisoned 0xAA before every timed launch
    hipMemsetAsync(q2, 0, (size_t)N_NUM * C_NUM * sizeof(float), stream);
    hipMemsetAsync(out, 0, sizeof(float), stream);

    qkern<<<dim3(NBB, N_NUM), 256, 0, stream>>>(W, labels, cov, q2);
    losskern<<<N_NUM, 256, 0, stream>>>(W, ys, labels, lam, means, meant, q2, out);
}